// Round 10
// baseline (408.936 us; speedup 1.0000x reference)
//
#include <hip/hip_runtime.h>
#include <hip/hip_bf16.h>
#include <stdint.h>

// EfficientAttentionBlock: 8x8 window attention. B=4, C=256, H=W=256.
// Round 10: 2-window pair blocks (512 thr) with NO Q/K LDS staging: each
// wave computes full K + own-quarter Q in registers (redundant-K, verified
// C-reg->operand identity from round 5's dV path). P crosses waves via a
// 4KB half-buffer (k 0..31 then 32..63), plain lq-block addressing. LDS
// 75776/block -> 2 blocks/CU (16 waves). ph3/ph4/epilogue byte-identical
// to verified round-8. ws: bf16 wq[32][256]@0, wk@8192, wv[256][256]@16384.

#define CIN    256
#define WIMG   256
#define CH_STRIDE 65536   // H*W

typedef __bf16 bf16x8 __attribute__((ext_vector_type(8)));
typedef float  f32x4  __attribute__((ext_vector_type(4)));

// Per-half-window LDS (bytes): Xt 32KB + P half-buffer 5KB (64 rows x 80B)
#define XT_OFF 0
#define PT_OFF 32768
#define HALF_LDS 37888    // pair block: 75776 -> 2 blocks/CU

__device__ __forceinline__ int swz8(int p) { return (p ^ (p >> 3)) & 7; }

__device__ __forceinline__ uint32_t pack2(float lo, float hi) {
  union { __bf16 h[2]; uint32_t u; } un;
  un.h[0] = (__bf16)lo; un.h[1] = (__bf16)hi;
  return un.u;
}

union fragu { uint32_t u[4]; bf16x8 v; };

// ---------------- weight prep: fp32 -> bf16 row-major -----------------------
__global__ __launch_bounds__(256) void wprep_kernel(
    const float* __restrict__ wq, const float* __restrict__ wk,
    const float* __restrict__ wv, __bf16* __restrict__ out)
{
  int i = blockIdx.x * 256 + threadIdx.x;   // 20480 threads x 4 elems = 81920
  int off = i * 4;
  const float* src;
  if (off < 8192)       src = wq + off;
  else if (off < 16384) src = wk + (off - 8192);
  else                  src = wv + (off - 16384);
  float4 v = *(const float4*)src;
  __bf16 h[4] = {(__bf16)v.x, (__bf16)v.y, (__bf16)v.z, (__bf16)v.w};
  *(uint2*)(out + off) = *(const uint2*)h;
}

__global__ __launch_bounds__(512) void win_attn_kernel(
    const float* __restrict__ x,  const __bf16* __restrict__ wsb,
    const float* __restrict__ bq, const float* __restrict__ bk,
    const float* __restrict__ bv, const float* __restrict__ gamma,
    float* __restrict__ out, int nblk)
{
  extern __shared__ __attribute__((aligned(16))) unsigned char lds_raw[];

  int t = threadIdx.x;
  int half = t >> 8;               // 0: window ww, 1: window ww+1
  int tt = t & 255;
  unsigned char* ldsb = lds_raw + half * HALF_LDS;

  // XCD-aware swizzle over 2048 blocks (divisible by 8).
  int bid   = blockIdx.x;
  int chunk = nblk >> 3;
  int swz   = (bid & 7) * chunk + (bid >> 3);
  int b   = swz >> 9;              // 512 pair-blocks per image (32 hw x 16 wwp)
  int hw  = (swz >> 4) & 31;
  int wwp = swz & 15;
  int ww  = wwp * 2 + half;
  size_t win_off = (size_t)b * (CIN * CH_STRIDE) + (size_t)hw * 8 * WIMG + (size_t)ww * 8;
  const float* xw = x + win_off;
  float* ow = out + win_off;

  int w = tt >> 6, l = tt & 63, l16 = l & 15, lq = l >> 4;
  float g = gamma[0];

  // ---------------- ph0: global x -> Xt (bf16, swizzled) --------------------
  #pragma unroll
  for (int it = 0; it < 8; ++it) {
    int id   = it * 256 + tt;
    int hf   = id & 1;
    int i    = (id >> 1) & 7;
    int c2   = id >> 4;
    const float* r0 = xw + (size_t)(2 * c2) * CH_STRIDE + i * WIMG + hf * 4;
    float4 va = *(const float4*)r0;
    float4 vb = *(const float4*)(r0 + CH_STRIDE);
    float ax[4] = {va.x, va.y, va.z, va.w};
    float bx[4] = {vb.x, vb.y, vb.z, vb.w};
    int blk = c2 >> 2;
    int sub = (c2 & 3) * 4;
    #pragma unroll
    for (int jj = 0; jj < 4; ++jj) {
      int p = i * 8 + hf * 4 + jj;
      *(uint32_t*)(ldsb + XT_OFF + p * 512 + ((blk ^ swz8(p)) << 4) + sub) =
          pack2(ax[jj], bx[jj]);
    }
  }
  __syncthreads();   // B1: Xt visible

  // ---------------- ph1: full K + own-quarter Q, all in registers -----------
  // kacc[qi][j]: C tile of mfma(wkf[row=j*16+l16], xb[qi]) -> col=pk, rows=chout
  // qacc[j]: same for Q with xb[w] (own pq block) only.
  fragu kf[4], qf;
  {
    f32x4 kacc[4][2] = {};
    f32x4 qacc[2] = {};
    const __bf16* wqrow = wsb + l16 * 256 + lq * 8;
    const __bf16* wkrow = wsb + 8192 + l16 * 256 + lq * 8;
    #pragma unroll
    for (int ks = 0; ks < 8; ++ks) {
      bf16x8 xb[4];
      #pragma unroll
      for (int qi = 0; qi < 4; ++qi) {
        int p = qi * 16 + l16;
        xb[qi] = *(const bf16x8*)(ldsb + XT_OFF + p * 512 +
                                  (((ks * 4 + lq) ^ swz8(p)) << 4));
      }
      #pragma unroll
      for (int j = 0; j < 2; ++j) {
        bf16x8 wkf = *(const bf16x8*)(wkrow + j * 16 * 256 + ks * 32);
        bf16x8 wqf = *(const bf16x8*)(wqrow + j * 16 * 256 + ks * 32);
        qacc[j] = __builtin_amdgcn_mfma_f32_16x16x32_bf16(wqf, xb[w], qacc[j], 0, 0, 0);
        #pragma unroll
        for (int qi = 0; qi < 4; ++qi)
          kacc[qi][j] = __builtin_amdgcn_mfma_f32_16x16x32_bf16(wkf, xb[qi], kacc[qi][j], 0, 0, 0);
      }
    }
    // pack with bias: k-dim = chout, two stacked 16-halves (j=0,1)
    float4 bq0 = *(const float4*)(bq + lq * 4);
    float4 bq1 = *(const float4*)(bq + 16 + lq * 4);
    float4 bk0 = *(const float4*)(bk + lq * 4);
    float4 bk1 = *(const float4*)(bk + 16 + lq * 4);
    qf.u[0] = pack2(qacc[0][0] + bq0.x, qacc[0][1] + bq0.y);
    qf.u[1] = pack2(qacc[0][2] + bq0.z, qacc[0][3] + bq0.w);
    qf.u[2] = pack2(qacc[1][0] + bq1.x, qacc[1][1] + bq1.y);
    qf.u[3] = pack2(qacc[1][2] + bq1.z, qacc[1][3] + bq1.w);
    #pragma unroll
    for (int qi = 0; qi < 4; ++qi) {
      kf[qi].u[0] = pack2(kacc[qi][0][0] + bk0.x, kacc[qi][0][1] + bk0.y);
      kf[qi].u[1] = pack2(kacc[qi][0][2] + bk0.z, kacc[qi][0][3] + bk0.w);
      kf[qi].u[2] = pack2(kacc[qi][1][0] + bk1.x, kacc[qi][1][1] + bk1.y);
      kf[qi].u[3] = pack2(kacc[qi][1][2] + bk1.z, kacc[qi][1][3] + bk1.w);
    }
  }

  // ---------------- ph2: S^T = mfma(K, Q), softmax in-register --------------
  // sacc[qi][r] = S[pk = qi*16 + lq*4 + r][pq = w*16 + l16]
  uint32_t dP[4][2];
  {
    f32x4 sacc[4];
    #pragma unroll
    for (int qi = 0; qi < 4; ++qi) {
      f32x4 z = {0.f, 0.f, 0.f, 0.f};
      sacc[qi] = __builtin_amdgcn_mfma_f32_16x16x32_bf16(kf[qi].v, qf.v, z, 0, 0, 0);
    }
    float e[4][4];
    float mx = -1e30f;
    #pragma unroll
    for (int qi = 0; qi < 4; ++qi)
      #pragma unroll
      for (int r = 0; r < 4; ++r) {
        float v = sacc[qi][r] * 0.125f;
        e[qi][r] = v;
        mx = fmaxf(mx, v);
      }
    mx = fmaxf(mx, __shfl_xor(mx, 16));
    mx = fmaxf(mx, __shfl_xor(mx, 32));
    float s = 0.f;
    #pragma unroll
    for (int qi = 0; qi < 4; ++qi)
      #pragma unroll
      for (int r = 0; r < 4; ++r) {
        e[qi][r] = __expf(e[qi][r] - mx);
        s += e[qi][r];
      }
    s += __shfl_xor(s, 16);
    s += __shfl_xor(s, 32);
    float inv = 1.0f / s;
    #pragma unroll
    for (int qi = 0; qi < 4; ++qi) {
      dP[qi][0] = pack2(e[qi][0] * inv, e[qi][1] * inv);
      dP[qi][1] = pack2(e[qi][2] * inv, e[qi][3] * inv);
    }
  }

  // ---- P half 0 (k = 0..31) -> LDS: b128 at (row q, block lq) --------------
  {
    int q = w * 16 + l16;
    uint4 p0; p0.x = dP[0][0]; p0.y = dP[0][1]; p0.z = dP[1][0]; p0.w = dP[1][1];
    *(uint4*)(ldsb + PT_OFF + q * 80 + lq * 16) = p0;
  }

  // ---------------- ph3: V^T = mfma(X, Wv) ----------------------------------
  // dV[pi][ci] dwords: V[c = w*64+ci*16+l16][vp = pi*16 + lq*4 + r], r=0..3
  uint32_t dV[4][4][2];
  {
    f32x4 vacc[4][4] = {};
    const __bf16* vrow = wsb + 16384 + (w * 64 + l16) * 256 + lq * 8;
    #pragma unroll
    for (int ks = 0; ks < 8; ++ks) {
      bf16x8 wvf[4];
      #pragma unroll
      for (int ci = 0; ci < 4; ++ci)
        wvf[ci] = *(const bf16x8*)(vrow + ci * 16 * 256 + ks * 32);
      bf16x8 xb[4];
      #pragma unroll
      for (int pi = 0; pi < 4; ++pi) {
        int p = pi * 16 + l16;
        xb[pi] = *(const bf16x8*)(ldsb + XT_OFF + p * 512 +
                                  (((ks * 4 + lq) ^ swz8(p)) << 4));
      }
      #pragma unroll
      for (int ci = 0; ci < 4; ++ci) {
        #pragma unroll
        for (int pi = 0; pi < 4; ++pi)
          vacc[pi][ci] = __builtin_amdgcn_mfma_f32_16x16x32_bf16(xb[pi], wvf[ci], vacc[pi][ci], 0, 0, 0);
      }
    }
    #pragma unroll
    for (int pi = 0; pi < 4; ++pi)
      #pragma unroll
      for (int ci = 0; ci < 4; ++ci) {
        dV[pi][ci][0] = pack2(vacc[pi][ci][0], vacc[pi][ci][1]);
        dV[pi][ci][1] = pack2(vacc[pi][ci][2], vacc[pi][ci][3]);
      }
  }
  __syncthreads();   // B2: P half 0 visible

  // ---------------- ph4 ks=0: O^T += P(k0..31) x V(k0..31) ------------------
  f32x4 oacc[4][4] = {};
  {
    bf16x8 Pf[4];
    #pragma unroll
    for (int bj = 0; bj < 4; ++bj)
      Pf[bj] = *(const bf16x8*)(ldsb + PT_OFF + (bj * 16 + l16) * 80 + lq * 16);
    #pragma unroll
    for (int ci = 0; ci < 4; ++ci) {
      fragu Vf;
      Vf.u[0] = dV[0][ci][0]; Vf.u[1] = dV[0][ci][1];
      Vf.u[2] = dV[1][ci][0]; Vf.u[3] = dV[1][ci][1];
      #pragma unroll
      for (int bj = 0; bj < 4; ++bj)
        oacc[ci][bj] = __builtin_amdgcn_mfma_f32_16x16x32_bf16(Pf[bj], Vf.v, oacc[ci][bj], 0, 0, 0);
    }
  }
  __syncthreads();   // B3: P half 0 consumed

  // ---- P half 1 (k = 32..63) -> LDS ----------------------------------------
  {
    int q = w * 16 + l16;
    uint4 p1; p1.x = dP[2][0]; p1.y = dP[2][1]; p1.z = dP[3][0]; p1.w = dP[3][1];
    *(uint4*)(ldsb + PT_OFF + q * 80 + lq * 16) = p1;
  }
  __syncthreads();   // B4: P half 1 visible

  // ---------------- ph4 ks=1: O^T += P(k32..63) x V(k32..63) ----------------
  {
    bf16x8 Pf[4];
    #pragma unroll
    for (int bj = 0; bj < 4; ++bj)
      Pf[bj] = *(const bf16x8*)(ldsb + PT_OFF + (bj * 16 + l16) * 80 + lq * 16);
    #pragma unroll
    for (int ci = 0; ci < 4; ++ci) {
      fragu Vf;
      Vf.u[0] = dV[2][ci][0]; Vf.u[1] = dV[2][ci][1];
      Vf.u[2] = dV[3][ci][0]; Vf.u[3] = dV[3][ci][1];
      #pragma unroll
      for (int bj = 0; bj < 4; ++bj)
        oacc[ci][bj] = __builtin_amdgcn_mfma_f32_16x16x32_bf16(Pf[bj], Vf.v, oacc[ci][bj], 0, 0, 0);
    }
  }

  // ---------------- epilogue: out = g*(O + bv) + x, float4 stores -----------
  // Halves write [0,32) and [32,64) of each 64B sector in the same phase.
  #pragma unroll
  for (int ci = 0; ci < 4; ++ci) {
    int c = w * 64 + ci * 16 + l16;
    size_t cbase = (size_t)c * CH_STRIDE;
    float bvc = bv[c];
    int chi = c >> 3, clo = (c & 7) * 2;
    #pragma unroll
    for (int bj = 0; bj < 4; ++bj) {
      int p0 = bj * 16 + lq * 4;
      float xr[4];
      #pragma unroll
      for (int r = 0; r < 4; ++r) {
        int p = p0 + r;
        xr[r] = (float)(*(const __bf16*)(ldsb + XT_OFF + p * 512 +
                                         ((chi ^ swz8(p)) << 4) + clo));
      }
      float4 o;
      o.x = g * (oacc[ci][bj][0] + bvc) + xr[0];
      o.y = g * (oacc[ci][bj][1] + bvc) + xr[1];
      o.z = g * (oacc[ci][bj][2] + bvc) + xr[2];
      o.w = g * (oacc[ci][bj][3] + bvc) + xr[3];
      *(float4*)(ow + cbase + (size_t)(p0 >> 3) * WIMG + (p0 & 7)) = o;
    }
  }
}

extern "C" void kernel_launch(void* const* d_in, const int* in_sizes, int n_in,
                              void* d_out, int out_size, void* d_ws, size_t ws_size,
                              hipStream_t stream) {
  const float* x     = (const float*)d_in[0];
  const float* wq    = (const float*)d_in[1];
  const float* bq    = (const float*)d_in[2];
  const float* wk    = (const float*)d_in[3];
  const float* bk    = (const float*)d_in[4];
  const float* wv    = (const float*)d_in[5];
  const float* bv    = (const float*)d_in[6];
  const float* gamma = (const float*)d_in[7];
  float* out = (float*)d_out;
  __bf16* wsb = (__bf16*)d_ws;

  // allow 75776B dynamic LDS (idempotent, host-side, capture-safe)
  hipFuncSetAttribute((const void*)win_attn_kernel,
                      hipFuncAttributeMaxDynamicSharedMemorySize, 2 * HALF_LDS);

  wprep_kernel<<<dim3(80), dim3(256), 0, stream>>>(wq, wk, wv, wsb);

  int B = in_sizes[0] / (CIN * CH_STRIDE);   // 4
  int nblk = B * 512;                        // window pairs: 32 hw x 16 wwp
  win_attn_kernel<<<dim3(nblk), dim3(512), 2 * HALF_LDS, stream>>>(
      x, wsb, bq, bk, bv, gamma, out, nblk);
}

// Round 11
// 245.970 us; speedup vs baseline: 1.6625x; 1.6625x over previous
//
#include <hip/hip_runtime.h>
#include <hip/hip_bf16.h>
#include <stdint.h>

// EfficientAttentionBlock: 8x8 window attention. B=4, C=256, H=W=256.
// Round 11: channel-chunked Xt (2 x 128ch, 16KB) with fused Q/K/V chunk
// accumulation -> per-pair LDS 48KB -> 2-3 blocks/CU (16-24 waves, vs R8's
// 8). Epilogue residual: ch128-255 from LDS chunk1, ch0-127 re-read global
// (L2-warm). All R8-verified machinery retained (pair blocks, Qt/Kt, sigma
// P-buffer, O^T ph4, paired float4 stores).
// ws: bf16 weights: wq[32][256]@0, wk@8192, wv[256][256]@16384 (elems).

#define CIN    256
#define WIMG   256
#define CH_STRIDE 65536   // H*W

typedef __bf16 bf16x8 __attribute__((ext_vector_type(8)));
typedef float  f32x4  __attribute__((ext_vector_type(4)));

// Per-window LDS (bytes): Xt chunk [64px][128ch] bf16 = 16KB; Qt 4K + Kt 4K
// (P 8K overlays Qt/Kt after ph2). Total 24576; pair block 49152.
#define XT_OFF 0
#define QT_OFF 16384
#define KT_OFF 20480
#define PT_OFF 16384
#define HALF_LDS 24576

__device__ __forceinline__ int swz8(int p) { return (p ^ (p >> 3)) & 7; }

__device__ __forceinline__ uint32_t pack2(float lo, float hi) {
  union { __bf16 h[2]; uint32_t u; } un;
  un.h[0] = (__bf16)lo; un.h[1] = (__bf16)hi;
  return un.u;
}

union fragu { uint32_t u[4]; bf16x8 v; };

// ---------------- weight prep: fp32 -> bf16 row-major -----------------------
__global__ __launch_bounds__(256) void wprep_kernel(
    const float* __restrict__ wq, const float* __restrict__ wk,
    const float* __restrict__ wv, __bf16* __restrict__ out)
{
  int i = blockIdx.x * 256 + threadIdx.x;   // 20480 threads x 4 elems = 81920
  int off = i * 4;
  const float* src;
  if (off < 8192)       src = wq + off;
  else if (off < 16384) src = wk + (off - 8192);
  else                  src = wv + (off - 16384);
  float4 v = *(const float4*)src;
  __bf16 h[4] = {(__bf16)v.x, (__bf16)v.y, (__bf16)v.z, (__bf16)v.w};
  *(uint2*)(out + off) = *(const uint2*)h;
}

__global__ __launch_bounds__(512) void win_attn_kernel(
    const float* __restrict__ x,  const __bf16* __restrict__ wsb,
    const float* __restrict__ bq, const float* __restrict__ bk,
    const float* __restrict__ bv, const float* __restrict__ gamma,
    float* __restrict__ out, int nblk)
{
  extern __shared__ __attribute__((aligned(16))) unsigned char lds_raw[];

  int t = threadIdx.x;
  int half = t >> 8;               // 0: window ww, 1: window ww+1
  int tt = t & 255;
  unsigned char* ldsb = lds_raw + half * HALF_LDS;

  // XCD-aware swizzle over 2048 blocks (divisible by 8).
  int bid   = blockIdx.x;
  int chunkb = nblk >> 3;
  int swz   = (bid & 7) * chunkb + (bid >> 3);
  int b   = swz >> 9;              // 512 pair-blocks per image (32 hw x 16 wwp)
  int hw  = (swz >> 4) & 31;
  int wwp = swz & 15;
  int ww  = wwp * 2 + half;
  size_t win_off = (size_t)b * (CIN * CH_STRIDE) + (size_t)hw * 8 * WIMG + (size_t)ww * 8;
  const float* xw = x + win_off;
  float* ow = out + win_off;

  int w = tt >> 6, l = tt & 63, l16 = l & 15, lq = l >> 4;
  float g = gamma[0];

  // ---------------- ph0+ph1 fused over 2 channel chunks ---------------------
  // wave w: Q rows (w<2, qkrow) or K rows (w>=2); V rows w*64..+64 always.
  int qkrow = (w & 1) * 16;
  f32x4 qacc[4]    = {};
  f32x4 vacc[4][4] = {};
  const __bf16* wqkrow = wsb + ((w < 2) ? 0 : 8192) + (qkrow + l16) * 256 + lq * 8;
  const __bf16* vrow   = wsb + 16384 + (w * 64 + l16) * 256 + lq * 8;

  #pragma unroll
  for (int ck = 0; ck < 2; ++ck) {
    // ---- chunk load: 128 channels -> Xt [64 px][128 ch] bf16 swizzled ----
    #pragma unroll
    for (int it = 0; it < 4; ++it) {
      int id   = it * 256 + tt;
      int hf   = id & 1;
      int i    = (id >> 1) & 7;
      int c2   = id >> 4;          // 0..63 channel-pair within chunk
      const float* r0 = xw + (size_t)(ck * 128 + 2 * c2) * CH_STRIDE + i * WIMG + hf * 4;
      float4 va = *(const float4*)r0;
      float4 vb = *(const float4*)(r0 + CH_STRIDE);
      float ax[4] = {va.x, va.y, va.z, va.w};
      float bx[4] = {vb.x, vb.y, vb.z, vb.w};
      int blk = c2 >> 2;           // 0..15
      int sub = (c2 & 3) * 4;
      #pragma unroll
      for (int jj = 0; jj < 4; ++jj) {
        int p = i * 8 + hf * 4 + jj;
        *(uint32_t*)(ldsb + XT_OFF + p * 256 + ((blk ^ swz8(p)) << 4) + sub) =
            pack2(ax[jj], bx[jj]);
      }
    }
    __syncthreads();   // chunk visible

    // ---- accumulate Q/K and V over this chunk (K=128) ----
    #pragma unroll
    for (int ks = 0; ks < 4; ++ks) {
      bf16x8 wvf[4];
      #pragma unroll
      for (int ci = 0; ci < 4; ++ci)
        wvf[ci] = *(const bf16x8*)(vrow + ci * 16 * 256 + ck * 128 + ks * 32);
      bf16x8 wqkf = *(const bf16x8*)(wqkrow + ck * 128 + ks * 32);
      bf16x8 xb[4];
      #pragma unroll
      for (int qi = 0; qi < 4; ++qi) {
        int p = qi * 16 + l16;
        xb[qi] = *(const bf16x8*)(ldsb + XT_OFF + p * 256 +
                                  (((ks * 4 + lq) ^ swz8(p)) << 4));
      }
      #pragma unroll
      for (int qi = 0; qi < 4; ++qi)
        qacc[qi] = __builtin_amdgcn_mfma_f32_16x16x32_bf16(wqkf, xb[qi], qacc[qi], 0, 0, 0);
      #pragma unroll
      for (int ci = 0; ci < 4; ++ci) {
        #pragma unroll
        for (int pi = 0; pi < 4; ++pi)
          vacc[pi][ci] = __builtin_amdgcn_mfma_f32_16x16x32_bf16(xb[pi], wvf[ci], vacc[pi][ci], 0, 0, 0);
      }
    }
    if (ck == 0) __syncthreads();   // chunk0 consumed before overwrite
  }

  // ---- Qt/Kt store (+bias), [64 px][32 ch] stride 64B, XOR swizzle ---------
  {
    const float* bias = (w < 2) ? bq : bk;
    int lbase = (w < 2) ? QT_OFF : KT_OFF;
    #pragma unroll
    for (int r = 0; r < 4; ++r) {
      int c = qkrow + lq * 4 + r;
      float bb = bias[c];
      #pragma unroll
      for (int qi = 0; qi < 4; ++qi) {
        int p = qi * 16 + l16;
        *(__bf16*)(ldsb + lbase + p * 64 + (((c >> 3) ^ (p & 3)) << 4) + (c & 7) * 2) =
            (__bf16)(qacc[qi][r] + bb);
      }
    }
  }
  __syncthreads();   // B2: Qt/Kt visible

  // ---------------- ph2: S^T = mfma(K, Q), softmax in-register --------------
  uint32_t dP[4][2];
  {
    int pq = w * 16 + l16;
    bf16x8 qa = *(const bf16x8*)(ldsb + QT_OFF + pq * 64 + ((lq ^ (pq & 3)) << 4));
    f32x4 sacc[4];
    #pragma unroll
    for (int qi = 0; qi < 4; ++qi) {
      int pk = qi * 16 + l16;
      bf16x8 kb = *(const bf16x8*)(ldsb + KT_OFF + pk * 64 + ((lq ^ (pk & 3)) << 4));
      f32x4 z = {0.f, 0.f, 0.f, 0.f};
      sacc[qi] = __builtin_amdgcn_mfma_f32_16x16x32_bf16(kb, qa, z, 0, 0, 0);
    }
    float e[4][4];
    float mx = -1e30f;
    #pragma unroll
    for (int qi = 0; qi < 4; ++qi)
      #pragma unroll
      for (int r = 0; r < 4; ++r) {
        float v = sacc[qi][r] * 0.125f;
        e[qi][r] = v;
        mx = fmaxf(mx, v);
      }
    mx = fmaxf(mx, __shfl_xor(mx, 16));
    mx = fmaxf(mx, __shfl_xor(mx, 32));
    float s = 0.f;
    #pragma unroll
    for (int qi = 0; qi < 4; ++qi)
      #pragma unroll
      for (int r = 0; r < 4; ++r) {
        e[qi][r] = __expf(e[qi][r] - mx);
        s += e[qi][r];
      }
    s += __shfl_xor(s, 16);
    s += __shfl_xor(s, 32);
    float inv = 1.0f / s;
    #pragma unroll
    for (int qi = 0; qi < 4; ++qi) {
      dP[qi][0] = pack2(e[qi][0] * inv, e[qi][1] * inv);
      dP[qi][1] = pack2(e[qi][2] * inv, e[qi][3] * inv);
    }
  }

  // ---- pack V accumulators to bf16 fragments -------------------------------
  uint32_t dV[4][4][2];
  #pragma unroll
  for (int pi = 0; pi < 4; ++pi)
    #pragma unroll
    for (int ci = 0; ci < 4; ++ci) {
      dV[pi][ci][0] = pack2(vacc[pi][ci][0], vacc[pi][ci][1]);
      dV[pi][ci][1] = pack2(vacc[pi][ci][2], vacc[pi][ci][3]);
    }
  __syncthreads();   // B3: Qt/Kt reads complete -> P may overlay

  // ---------------- P -> LDS (sigma-stored, XOR-swizzled) -------------------
  {
    int q = w * 16 + l16;
    int qm = q & 7;
    #pragma unroll
    for (int qi = 0; qi < 4; ++qi) {
      int blk = (((qi >> 1) * 4) + lq) ^ qm;
      uint2 val; val.x = dP[qi][0]; val.y = dP[qi][1];
      *(uint2*)(ldsb + PT_OFF + q * 128 + blk * 16 + (qi & 1) * 8) = val;
    }
  }
  __syncthreads();   // B4: P visible

  // ---------------- ph4: O^T = mfma(P, V) -----------------------------------
  f32x4 oacc[4][4] = {};
  #pragma unroll
  for (int ks = 0; ks < 2; ++ks) {
    bf16x8 Pf[4];
    #pragma unroll
    for (int bj = 0; bj < 4; ++bj) {
      int q = bj * 16 + l16;
      int blk = (ks * 4 + lq) ^ (q & 7);
      Pf[bj] = *(const bf16x8*)(ldsb + PT_OFF + q * 128 + blk * 16);
    }
    #pragma unroll
    for (int ci = 0; ci < 4; ++ci) {
      fragu Vf;
      Vf.u[0] = dV[2 * ks][ci][0];
      Vf.u[1] = dV[2 * ks][ci][1];
      Vf.u[2] = dV[2 * ks + 1][ci][0];
      Vf.u[3] = dV[2 * ks + 1][ci][1];
      #pragma unroll
      for (int bj = 0; bj < 4; ++bj)
        oacc[ci][bj] = __builtin_amdgcn_mfma_f32_16x16x32_bf16(Pf[bj], Vf.v, oacc[ci][bj], 0, 0, 0);
    }
  }

  // ---------------- epilogue: out = g*(O + bv) + x, float4 stores -----------
  // w>=2 (c 128..255): residual from LDS chunk1. w<2 (c 0..127): global x.
  #pragma unroll
  for (int ci = 0; ci < 4; ++ci) {
    int c = w * 64 + ci * 16 + l16;
    size_t cbase = (size_t)c * CH_STRIDE;
    float bvc = bv[c];
    #pragma unroll
    for (int bj = 0; bj < 4; ++bj) {
      int p0 = bj * 16 + lq * 4;
      size_t off = cbase + (size_t)(p0 >> 3) * WIMG + (p0 & 7);
      float xr[4];
      if (w >= 2) {
        int cc = c - 128;
        int blk = cc >> 3;
        int sub = ((cc >> 1) & 3) * 4 + (cc & 1) * 2;
        #pragma unroll
        for (int r = 0; r < 4; ++r) {
          int p = p0 + r;
          xr[r] = (float)(*(const __bf16*)(ldsb + XT_OFF + p * 256 +
                                           ((blk ^ swz8(p)) << 4) + sub));
        }
      } else {
        float4 xv = *(const float4*)(xw + off);
        xr[0] = xv.x; xr[1] = xv.y; xr[2] = xv.z; xr[3] = xv.w;
      }
      float4 o;
      o.x = g * (oacc[ci][bj][0] + bvc) + xr[0];
      o.y = g * (oacc[ci][bj][1] + bvc) + xr[1];
      o.z = g * (oacc[ci][bj][2] + bvc) + xr[2];
      o.w = g * (oacc[ci][bj][3] + bvc) + xr[3];
      *(float4*)(ow + off) = o;
    }
  }
}

extern "C" void kernel_launch(void* const* d_in, const int* in_sizes, int n_in,
                              void* d_out, int out_size, void* d_ws, size_t ws_size,
                              hipStream_t stream) {
  const float* x     = (const float*)d_in[0];
  const float* wq    = (const float*)d_in[1];
  const float* bq    = (const float*)d_in[2];
  const float* wk    = (const float*)d_in[3];
  const float* bk    = (const float*)d_in[4];
  const float* wv    = (const float*)d_in[5];
  const float* bv    = (const float*)d_in[6];
  const float* gamma = (const float*)d_in[7];
  float* out = (float*)d_out;
  __bf16* wsb = (__bf16*)d_ws;

  // allow 48KB dynamic LDS (idempotent, host-side, capture-safe)
  hipFuncSetAttribute((const void*)win_attn_kernel,
                      hipFuncAttributeMaxDynamicSharedMemorySize, 2 * HALF_LDS);

  wprep_kernel<<<dim3(80), dim3(256), 0, stream>>>(wq, wk, wv, wsb);

  int B = in_sizes[0] / (CIN * CH_STRIDE);   // 4
  int nblk = B * 512;                        // window pairs: 32 hw x 16 wwp
  win_attn_kernel<<<dim3(nblk), dim3(512), 2 * HALF_LDS, stream>>>(
      x, wsb, bq, bk, bv, gamma, out, nblk);
}